// Round 8
// baseline (90.797 us; speedup 1.0000x reference)
//
#include <hip/hip_runtime.h>

#define NB   4
#define KCH  4
#define P    4096          // 64*64 downsampled points per batch
#define REC  12            // LDS floats per q-record: fx,fy,fr,fg,fb,h,s0..s3,pad,pad
#define QT   64            // q per block
#define BLK  256           // threads per block
#define PT   2             // p per thread (p-tile = 512)
#define NPT  8             // p-tiles per batch
#define NBLK 288           // triangle blocks per batch: sum(64-8*pt)
#define TOTB (NBLK * NB)   // 1152 blocks

#if __has_builtin(__builtin_amdgcn_exp2f)
#define EXPFN(x) __builtin_amdgcn_exp2f(x)
#define FSCALE 1.2011224087864498f   /* sqrt(log2(e)) */
#else
#define EXPFN(x) __expf(x)
#define FSCALE 1.0f
#endif

// Cross-launch accumulator. Graph-safe: the LAST block of every launch
// writes out[0] and resets both globals, so every replay starts from zero.
__device__ float    g_scratch = 0.0f;
__device__ unsigned g_count   = 0u;

// Compute one downsampled-point record directly from raw inputs (R5-proven).
__device__ __forceinline__ void make_rec(const float* __restrict__ images,
                                         const float* __restrict__ segs,
                                         int n, int p, float* o /*[10]*/) {
    int i = p >> 6;
    int j = p & 63;
    int off = 256 * i + 2 * j;
    const float* img = images + (size_t)n * 3 * 16384;
    float x = (float)j * (FSCALE / 50.0f);     // SIGMA_XY*SCALE = 50
    float y = (float)i * (FSCALE / 50.0f);
    float r = img[0 * 16384 + off] * (FSCALE / 15.0f);   // SIGMA_RGB = 15
    float g = img[1 * 16384 + off] * (FSCALE / 15.0f);
    float b = img[2 * 16384 + off] * (FSCALE / 15.0f);
    float h = -0.5f * (x * x + y * y + r * r + g * g + b * b);
    o[0] = x; o[1] = y; o[2] = r; o[3] = g; o[4] = b; o[5] = h;
    const float* sg = segs + (size_t)n * KCH * 16384;
#pragma unroll
    for (int k = 0; k < KCH; ++k) {
        float2 s0 = *(const float2*)(sg + k * 16384 + off);
        float2 s1 = *(const float2*)(sg + k * 16384 + off + 128);
        o[6 + k] = 0.25f * ((s0.x + s0.y) + (s1.x + s1.y));
    }
}

// Single fused kernel (R5-proven inner loop): inline prep + symmetric
// pairwise-Gaussian x seg-dot reduction over the block triangle.
// grid = (288 triangle blocks, 4 batches). ONE dispatch total.
__global__ __launch_bounds__(256) void crf_fused(const float* __restrict__ images,
                                                 const float* __restrict__ segs,
                                                 float* __restrict__ out) {
    __shared__ float lds[QT * REC];      // 3 KB
    __shared__ float wsum[BLK / 64];

    int t = threadIdx.x;
    int n = blockIdx.y;

    // Decode triangle block index -> (p-tile pt, q-chunk qc), qc >= 8*pt.
    static const int cum[NPT] = {0, 64, 120, 168, 208, 240, 264, 280};
    int b = blockIdx.x;                  // 0..287
    int pt = 0;
#pragma unroll
    for (int i = 1; i < NPT; ++i) pt += (b >= cum[i]) ? 1 : 0;
    int qc = b - cum[pt] + 8 * pt;
    int pbase = pt * (BLK * PT);
    int qbase = qc * QT;
    bool mixed = (qc >> 3) == pt;        // q-chunk overlaps the p-tile

    // q-records: first QT threads each build one record into LDS.
    if (t < QT) {
        float o[10];
        make_rec(images, segs, n, qbase + t, o);
        float* l = lds + t * REC;
        *(float4*)(l + 0) = make_float4(o[0], o[1], o[2], o[3]);
        *(float4*)(l + 4) = make_float4(o[4], o[5], o[6], o[7]);
        *(float2*)(l + 8) = make_float2(o[8], o[9]);
    }

    // p-records: every thread builds its PT own records into registers.
    float rp[PT][10];
#pragma unroll
    for (int pi = 0; pi < PT; ++pi)
        make_rec(images, segs, n, pbase + t + pi * BLK, rp[pi]);
    __syncthreads();

    float acc[PT] = {0.f, 0.f};
    float acc_all;

    if (!mixed) {
        // Strictly above the diagonal: every pair counts twice.
#pragma unroll 4
        for (int q = 0; q < QT; ++q) {
            const float4* rq = (const float4*)(lds + q * REC);  // broadcast
            float4 f0 = rq[0];
            float4 f1 = rq[1];
            float4 f2 = rq[2];
#pragma unroll
            for (int pi = 0; pi < PT; ++pi) {
                float d = rp[pi][5] + f1.y;
                d = fmaf(rp[pi][0], f0.x, d);
                d = fmaf(rp[pi][1], f0.y, d);
                d = fmaf(rp[pi][2], f0.z, d);
                d = fmaf(rp[pi][3], f0.w, d);
                d = fmaf(rp[pi][4], f1.x, d);
                float w = EXPFN(d);
                float sd = rp[pi][6] * f1.z;
                sd = fmaf(rp[pi][7], f1.w, sd);
                sd = fmaf(rp[pi][8], f2.x, sd);
                sd = fmaf(rp[pi][9], f2.y, sd);
                acc[pi] = fmaf(w, sd, acc[pi]);
            }
        }
        acc_all = 2.0f * (acc[0] + acc[1]);
    } else {
        // Diagonal-overlap block: weight pairs 2/1/0 for q>p / q==p / q<p.
#pragma unroll 4
        for (int q = 0; q < QT; ++q) {
            const float4* rq = (const float4*)(lds + q * REC);
            float4 f0 = rq[0];
            float4 f1 = rq[1];
            float4 f2 = rq[2];
            int qg = qbase + q;
#pragma unroll
            for (int pi = 0; pi < PT; ++pi) {
                int pg = pbase + t + pi * BLK;
                float d = rp[pi][5] + f1.y;
                d = fmaf(rp[pi][0], f0.x, d);
                d = fmaf(rp[pi][1], f0.y, d);
                d = fmaf(rp[pi][2], f0.z, d);
                d = fmaf(rp[pi][3], f0.w, d);
                d = fmaf(rp[pi][4], f1.x, d);
                float w = EXPFN(d);
                float sd = rp[pi][6] * f1.z;
                sd = fmaf(rp[pi][7], f1.w, sd);
                sd = fmaf(rp[pi][8], f2.x, sd);
                sd = fmaf(rp[pi][9], f2.y, sd);
                float f = (qg > pg) ? 2.0f : ((qg == pg) ? 1.0f : 0.0f);
                acc[pi] = fmaf(w, sd * f, acc[pi]);
            }
        }
        acc_all = acc[0] + acc[1];
    }

#pragma unroll
    for (int off = 32; off > 0; off >>= 1)
        acc_all += __shfl_down(acc_all, off, 64);
    if ((t & 63) == 0) wsum[t >> 6] = acc_all;
    __syncthreads();

    if (t == 0) {
        float s = (wsum[0] + wsum[1]) + (wsum[2] + wsum[3]);
        atomicAdd(&g_scratch, s);                 // device-scope (m20)
        __threadfence();
        unsigned prev = atomicAdd(&g_count, 1u);
        if (prev == TOTB - 1) {
            // Last block: every other block's add is fence-ordered before its
            // g_count increment, so all partials are visible here.
            __threadfence();
            float total = atomicAdd(&g_scratch, 0.0f);   // coherent read
            out[0] = total * (-2.5e-8f);   // loss = WEIGHT*(-sum/NB)
            atomicExch(&g_scratch, 0.0f);                // reset for next replay
            atomicExch(&g_count, 0u);
        }
    }
}

extern "C" void kernel_launch(void* const* d_in, const int* in_sizes, int n_in,
                              void* d_out, int out_size, void* d_ws, size_t ws_size,
                              hipStream_t stream) {
    const float* images = (const float*)d_in[0];
    const float* segs   = (const float*)d_in[1];
    float* out = (float*)d_out;
    (void)d_ws; (void)ws_size;

    crf_fused<<<dim3(NBLK, NB), dim3(256), 0, stream>>>(images, segs, out);
}

// Round 9
// 77.755 us; speedup vs baseline: 1.1677x; 1.1677x over previous
//
#include <hip/hip_runtime.h>

#define NB   4
#define KCH  4
#define P    4096          // 64*64 downsampled points per batch
#define REC  12            // LDS floats per q-record: fx,fy,fr,fg,fb,h,s0..s3,pad,pad
#define QT   64            // q per block
#define BLK  256           // threads per block
#define PT   2             // p per thread (p-tile = 512)
#define NPT  8             // p-tiles per batch
#define NBLK 288           // triangle blocks per batch: sum(64-8*pt)

#if __has_builtin(__builtin_amdgcn_exp2f)
#define EXPFN(x) __builtin_amdgcn_exp2f(x)
#define FSCALE 1.2011224087864498f   /* sqrt(log2(e)) */
#else
#define EXPFN(x) __expf(x)
#define FSCALE 1.0f
#endif

// Compute one downsampled-point record directly from raw inputs.
// feats pre-scaled by FSCALE = sqrt(log2 e) so exp2 needs no extra multiply;
// h = -0.5*|f|^2 (already in log2 units).
__device__ __forceinline__ void make_rec(const float* __restrict__ images,
                                         const float* __restrict__ segs,
                                         int n, int p, float* o /*[10]*/) {
    int i = p >> 6;
    int j = p & 63;
    int off = 256 * i + 2 * j;           // element offset of pixel (2i, 2j)
    const float* img = images + (size_t)n * 3 * 16384;
    float x = (float)j * (FSCALE / 50.0f);     // SIGMA_XY*SCALE = 50
    float y = (float)i * (FSCALE / 50.0f);
    float r = img[0 * 16384 + off] * (FSCALE / 15.0f);   // SIGMA_RGB = 15
    float g = img[1 * 16384 + off] * (FSCALE / 15.0f);
    float b = img[2 * 16384 + off] * (FSCALE / 15.0f);
    float h = -0.5f * (x * x + y * y + r * r + g * g + b * b);
    o[0] = x; o[1] = y; o[2] = r; o[3] = g; o[4] = b; o[5] = h;
    const float* sg = segs + (size_t)n * KCH * 16384;
#pragma unroll
    for (int k = 0; k < KCH; ++k) {
        float2 s0 = *(const float2*)(sg + k * 16384 + off);
        float2 s1 = *(const float2*)(sg + k * 16384 + off + 128);
        o[6 + k] = 0.25f * ((s0.x + s0.y) + (s1.x + s1.y));
    }
}

// Single fused kernel (best-measured R5 configuration): inline prep
// (p-records in regs, q-records in LDS) + symmetric pairwise-Gaussian x
// seg-dot reduction over the block triangle.
// grid = (288 triangle blocks, 4 batches).
// NOTE (R8 post-mortem): do NOT replace the memset+atomicAdd(out) epilogue
// with a cross-launch __device__-global reduction — the required
// __threadfence()s + single-cacheline device-scope atomics cost ~12 us.
__global__ __launch_bounds__(256) void crf_fused(const float* __restrict__ images,
                                                 const float* __restrict__ segs,
                                                 float* __restrict__ out) {
    __shared__ float lds[QT * REC];      // 3 KB
    __shared__ float wsum[BLK / 64];

    int t = threadIdx.x;
    int n = blockIdx.y;

    // Decode triangle block index -> (p-tile pt, q-chunk qc), qc >= 8*pt.
    static const int cum[NPT] = {0, 64, 120, 168, 208, 240, 264, 280};
    int b = blockIdx.x;                  // 0..287
    int pt = 0;
#pragma unroll
    for (int i = 1; i < NPT; ++i) pt += (b >= cum[i]) ? 1 : 0;
    int qc = b - cum[pt] + 8 * pt;
    int pbase = pt * (BLK * PT);
    int qbase = qc * QT;
    bool mixed = (qc >> 3) == pt;        // q-chunk overlaps the p-tile

    // q-records: first QT threads each build one record into LDS.
    if (t < QT) {
        float o[10];
        make_rec(images, segs, n, qbase + t, o);
        float* l = lds + t * REC;
        *(float4*)(l + 0) = make_float4(o[0], o[1], o[2], o[3]);
        *(float4*)(l + 4) = make_float4(o[4], o[5], o[6], o[7]);
        *(float2*)(l + 8) = make_float2(o[8], o[9]);
    }

    // p-records: every thread builds its PT own records into registers.
    float rp[PT][10];
#pragma unroll
    for (int pi = 0; pi < PT; ++pi)
        make_rec(images, segs, n, pbase + t + pi * BLK, rp[pi]);
    __syncthreads();

    float acc[PT] = {0.f, 0.f};
    float acc_all;

    if (!mixed) {
        // Strictly above the diagonal: every pair counts twice.
#pragma unroll 4
        for (int q = 0; q < QT; ++q) {
            const float4* rq = (const float4*)(lds + q * REC);  // broadcast
            float4 f0 = rq[0];
            float4 f1 = rq[1];
            float4 f2 = rq[2];
#pragma unroll
            for (int pi = 0; pi < PT; ++pi) {
                float d = rp[pi][5] + f1.y;
                d = fmaf(rp[pi][0], f0.x, d);
                d = fmaf(rp[pi][1], f0.y, d);
                d = fmaf(rp[pi][2], f0.z, d);
                d = fmaf(rp[pi][3], f0.w, d);
                d = fmaf(rp[pi][4], f1.x, d);
                float w = EXPFN(d);
                float sd = rp[pi][6] * f1.z;
                sd = fmaf(rp[pi][7], f1.w, sd);
                sd = fmaf(rp[pi][8], f2.x, sd);
                sd = fmaf(rp[pi][9], f2.y, sd);
                acc[pi] = fmaf(w, sd, acc[pi]);
            }
        }
        acc_all = 2.0f * (acc[0] + acc[1]);
    } else {
        // Diagonal-overlap block: weight pairs 2/1/0 for q>p / q==p / q<p.
#pragma unroll 4
        for (int q = 0; q < QT; ++q) {
            const float4* rq = (const float4*)(lds + q * REC);
            float4 f0 = rq[0];
            float4 f1 = rq[1];
            float4 f2 = rq[2];
            int qg = qbase + q;
#pragma unroll
            for (int pi = 0; pi < PT; ++pi) {
                int pg = pbase + t + pi * BLK;
                float d = rp[pi][5] + f1.y;
                d = fmaf(rp[pi][0], f0.x, d);
                d = fmaf(rp[pi][1], f0.y, d);
                d = fmaf(rp[pi][2], f0.z, d);
                d = fmaf(rp[pi][3], f0.w, d);
                d = fmaf(rp[pi][4], f1.x, d);
                float w = EXPFN(d);
                float sd = rp[pi][6] * f1.z;
                sd = fmaf(rp[pi][7], f1.w, sd);
                sd = fmaf(rp[pi][8], f2.x, sd);
                sd = fmaf(rp[pi][9], f2.y, sd);
                float f = (qg > pg) ? 2.0f : ((qg == pg) ? 1.0f : 0.0f);
                acc[pi] = fmaf(w, sd * f, acc[pi]);
            }
        }
        acc_all = acc[0] + acc[1];
    }

#pragma unroll
    for (int off = 32; off > 0; off >>= 1)
        acc_all += __shfl_down(acc_all, off, 64);
    if ((t & 63) == 0) wsum[t >> 6] = acc_all;
    __syncthreads();
    if (t == 0) {
        float s = (wsum[0] + wsum[1]) + (wsum[2] + wsum[3]);
        // loss = WEIGHT * (-sum / n) = -1e-7/4 * sum
        atomicAdd(out, s * (-2.5e-8f));
    }
}

extern "C" void kernel_launch(void* const* d_in, const int* in_sizes, int n_in,
                              void* d_out, int out_size, void* d_ws, size_t ws_size,
                              hipStream_t stream) {
    const float* images = (const float*)d_in[0];
    const float* segs   = (const float*)d_in[1];
    float* out = (float*)d_out;
    (void)d_ws; (void)ws_size;

    (void)hipMemsetAsync(out, 0, sizeof(float), stream);
    crf_fused<<<dim3(NBLK, NB), dim3(256), 0, stream>>>(images, segs, out);
}